// Round 3
// baseline (457.869 us; speedup 1.0000x reference)
//
#include <hip/hip_runtime.h>
#include <hip/hip_bf16.h>

// 3-layer MLP matvec chain, fp32. HBM-bound: 435 MB of single-use weight
// reads => 69 us floor at 6.3 TB/s achievable.
//
// R2 lesson: dur_us carries a ~300 us harness reset floor (1 GiB ws poison
// fill at 160 us + 417 MB input restore); our dispatches never crack the
// top-5 (all < 159 us). This round: wave-per-row structure tuned for the
// read ceiling -- no block-level reduce, no __syncthreads, 2 independent
// accumulator chains per wave, unroll-8 => ~24 16B loads in flight per wave,
// ~4 waves/SIMD occupancy. If dur_us doesn't move, kernels are at roofline
// and the remainder is harness floor.

template<int K>
__global__ __launch_bounds__(256) void matvec_wave2(
    const float* __restrict__ W,    // nrows x K row-major
    const float* __restrict__ x,    // K (L1/L2-resident: 16-32 KB)
    const float* __restrict__ bias, // nrows
    float* __restrict__ y,          // nrows
    int do_square)
{
    constexpr int K4 = K / 4;    // float4 per row
    constexpr int L  = K4 / 64;  // float4 per lane per row (16 or 32)

    const int wave = (blockIdx.x * 256 + threadIdx.x) >> 6; // global wave id
    const int lane = threadIdx.x & 63;
    const int row0 = wave * 2;   // 2 rows per wave

    const float4* __restrict__ Wa = (const float4*)(W + (size_t)row0 * K);
    const float4* __restrict__ Wb = Wa + K4;
    const float4* __restrict__ x4 = (const float4*)x;

    float acc0 = 0.0f, acc1 = 0.0f;
    #pragma unroll 8
    for (int j = 0; j < L; ++j) {
        const int i = lane + 64 * j;   // lanes read 1 KB contiguous per instr
        float4 v = x4[i];
        float4 a = Wa[i];
        float4 b = Wb[i];
        acc0 += a.x * v.x + a.y * v.y + a.z * v.z + a.w * v.w;
        acc1 += b.x * v.x + b.y * v.y + b.z * v.z + b.w * v.w;
    }

    // wave-64 butterfly reduce (both rows), no LDS, no syncthreads
    #pragma unroll
    for (int off = 32; off > 0; off >>= 1) {
        acc0 += __shfl_down(acc0, off, 64);
        acc1 += __shfl_down(acc1, off, 64);
    }

    if (lane == 0) {
        float r0 = acc0 + bias[row0];
        float r1 = acc1 + bias[row0 + 1];
        if (do_square) { r0 = r0 * r0; r1 = r1 * r1; }
        y[row0]     = r0;
        y[row0 + 1] = r1;
    }
}

extern "C" void kernel_launch(void* const* d_in, const int* in_sizes, int n_in,
                              void* d_out, int out_size, void* d_ws, size_t ws_size,
                              hipStream_t stream) {
    const float* x  = (const float*)d_in[0];
    const float* W1 = (const float*)d_in[1];
    const float* b1 = (const float*)d_in[2];
    const float* W2 = (const float*)d_in[3];
    const float* b2 = (const float*)d_in[4];
    const float* W3 = (const float*)d_in[5];
    const float* b3 = (const float*)d_in[6];
    float* out = (float*)d_out;

    const int D_HID = 8192, D_OUT = 1000;

    float* h1 = (float*)d_ws;          // 8192 floats
    float* h2 = h1 + D_HID;            // 8192 floats

    // grid: (rows/2 rows-per-wave) waves, 4 waves per 256-thread block
    // layer 1: h1 = (W1 @ x + b1)^2   -- 128 MiB, K=4096, 4096 waves
    matvec_wave2<4096><<<D_HID / 8, 256, 0, stream>>>(W1, x, b1, h1, 1);
    // layer 2: h2 = (W2 @ h1 + b2)^2  -- 256 MiB, K=8192, 4096 waves
    matvec_wave2<8192><<<D_HID / 8, 256, 0, stream>>>(W2, h1, b2, h2, 1);
    // layer 3: out = W3 @ h2 + b3     -- 32.8 MB, K=8192, 500 waves (125 blocks)
    matvec_wave2<8192><<<D_OUT / 8, 256, 0, stream>>>(W3, h2, b3, out, 0);
}